// Round 1
// baseline (4415.008 us; speedup 1.0000x reference)
//
#include <hip/hip_runtime.h>

// PPOInteractiveModel: B=16, V=50000, H=512, L=2, T=32, K=10.
// Key facts exploited:
//  - GRU hidden stays ZERO (reference returns old state) => gh = b_hh, w_hh unused.
//  - Sequential over T (selection feeds next input), so per-step kernel chain.
//  - Softmax without max-subtraction (logits |l| <~ 10): ordering by e^l*h is
//    monotone-identical to policy*h; ties break to lower index (matches jax).
//  - All reductions fixed-order; fully deterministic; fp32 throughout.

#define TT 32
#define BDIM 16
#define VD 50000
#define HD 512
#define NB3 782          // ceil(50000/64) FC blocks

// ws layout (float offsets)
#define WS_HIST 0              // 16*50000
#define WS_X0   800000         // 16*512
#define WS_X1   808192
#define WS_X2T  816384         // [512][16]
#define WS_SWS  824576         // 782*16
#define WS_TV   837088         // 782*16*10
#define WS_INVS 962208         // 16
#define WS_TI   962224         // 782*16*10 (int)
#define WS_FCWT 1088000        // 512*50000 (optional)

// d_out layout (float offsets)
#define O_IDS 25600000
#define O_VAL 25600512
#define O_FH  25601024
#define O_HIT 26401024

__global__ __launch_bounds__(256) void k_init(const float4* __restrict__ mask4,
                                              const float4* __restrict__ emb4,
                                              float4* __restrict__ hist4,
                                              float4* __restrict__ x04)
{
    for (int idx = blockIdx.x * 256 + threadIdx.x; idx < 202048; idx += 256 * 256) {
        if (idx < 200000) hist4[idx] = mask4[idx];
        else { int c = idx - 200000; x04[c] = emb4[c & 127]; }  // x0[b][d]=emb[0][d]
    }
}

__global__ __launch_bounds__(256) void k_transpose(const float* __restrict__ src,
                                                   float* __restrict__ dst)
{
    __shared__ float tile[64][65];
    const int bt = blockIdx.x, tv = bt >> 3, th = bt & 7;
    const int v0 = tv * 64, h0 = th * 64;
    const int tx = threadIdx.x & 63, ty4 = threadIdx.x >> 6;
    for (int p = 0; p < 16; p++) {
        int vr = p * 4 + ty4, v = v0 + vr;
        tile[vr][tx] = (v < VD) ? src[(size_t)v * HD + h0 + tx] : 0.f;
    }
    __syncthreads();
    for (int p = 0; p < 16; p++) {
        int hr = p * 4 + ty4, v = v0 + tx;
        if (v < VD) dst[(size_t)(h0 + hr) * VD + v] = tile[tx][hr];
    }
}

// GRU layer with zero hidden state. blocks 0..127: GRU (thread=(j,b,kq));
// blocks 128..383: normalize previous step's e-values in d_out by 1/S.
__global__ __launch_bounds__(256) void k_gru(const float* __restrict__ xin,
                                             float* __restrict__ xout,
                                             const float* __restrict__ W,
                                             const float* __restrict__ bi,
                                             const float* __restrict__ bh,
                                             int outT,
                                             float* __restrict__ dout,
                                             const float* __restrict__ invS,
                                             int tprev)
{
    if (blockIdx.x >= 128) {
        if (tprev < 0) return;
        for (int idx = (blockIdx.x - 128) * 256 + threadIdx.x; idx < 200000; idx += 256 * 256) {
            int b = idx / 12500, v4 = idx % 12500;
            float4* row = (float4*)(dout + ((size_t)b * TT + tprev) * VD);
            float4 e = row[v4]; float s = invS[b];
            e.x *= s; e.y *= s; e.z *= s; e.w *= s;
            row[v4] = e;
        }
        return;
    }
    const int tid = threadIdx.x;
    const int kq = tid & 3, b = (tid >> 2) & 15, jl = tid >> 6;
    const int j = blockIdx.x * 4 + jl;
    const float4* xr = (const float4*)(xin + (size_t)b * HD + kq * 128);
    const float4* wr = (const float4*)(W + (size_t)j * HD + kq * 128);
    const float4* wz = (const float4*)(W + (size_t)(j + 512) * HD + kq * 128);
    const float4* wn = (const float4*)(W + (size_t)(j + 1024) * HD + kq * 128);
    float4 aR = {0, 0, 0, 0}, aZ = {0, 0, 0, 0}, aN = {0, 0, 0, 0};
#pragma unroll 4
    for (int k = 0; k < 32; k++) {
        float4 x = xr[k];
        float4 r = wr[k];
        aR.x = fmaf(r.x, x.x, aR.x); aR.y = fmaf(r.y, x.y, aR.y);
        aR.z = fmaf(r.z, x.z, aR.z); aR.w = fmaf(r.w, x.w, aR.w);
        float4 z = wz[k];
        aZ.x = fmaf(z.x, x.x, aZ.x); aZ.y = fmaf(z.y, x.y, aZ.y);
        aZ.z = fmaf(z.z, x.z, aZ.z); aZ.w = fmaf(z.w, x.w, aZ.w);
        float4 n = wn[k];
        aN.x = fmaf(n.x, x.x, aN.x); aN.y = fmaf(n.y, x.y, aN.y);
        aN.z = fmaf(n.z, x.z, aN.z); aN.w = fmaf(n.w, x.w, aN.w);
    }
    float sR = (aR.x + aR.y) + (aR.z + aR.w);
    float sZ = (aZ.x + aZ.y) + (aZ.z + aZ.w);
    float sN = (aN.x + aN.y) + (aN.z + aN.w);
    sR += __shfl_xor(sR, 1, 64); sR += __shfl_xor(sR, 2, 64);
    sZ += __shfl_xor(sZ, 1, 64); sZ += __shfl_xor(sZ, 2, 64);
    sN += __shfl_xor(sN, 1, 64); sN += __shfl_xor(sN, 2, 64);
    if (kq == 0) {
        float gr = sR + bi[j] + bh[j];
        float gz = sZ + bi[512 + j] + bh[512 + j];
        float rr = 1.f / (1.f + expf(-gr));
        float zz = 1.f / (1.f + expf(-gz));
        float nn = tanhf(sN + bi[1024 + j] + rr * bh[1024 + j]);
        float o = (1.f - zz) * nn;   // + zz*h, h=0
        if (outT) xout[(size_t)j * 16 + b] = o;
        else      xout[(size_t)b * HD + j] = o;
    }
}

// FC + unnormalized softmax + per-block per-b top-10 of e*history.
// Block: 64 v-columns, 4 waves = K-split 4 (128 d each), acc[16] per thread.
// x2T is read with wave-uniform indices (readfirstlane on wave id) -> s_loads.
template<int TRANS>
__global__ __launch_bounds__(256, 2) void k3_fc(const float* __restrict__ W,
                                                const float* __restrict__ fcb,
                                                const float* __restrict__ x2T,
                                                const float* __restrict__ hist,
                                                float* __restrict__ dout,
                                                float* __restrict__ s_ws,
                                                float* __restrict__ tv_ws,
                                                int* __restrict__ ti_ws,
                                                int t)
{
    __shared__ float red[4][64][17];
    __shared__ float elds[64][17];
    const int tid = threadIdx.x;
    const int wave = tid >> 6, lane = tid & 63;
    const int khu = __builtin_amdgcn_readfirstlane(wave);
    const int vb0 = blockIdx.x * 64;
    const int v = vb0 + lane;
    float acc[16];
#pragma unroll
    for (int i = 0; i < 16; i++) acc[i] = 0.f;
    const float* xp = x2T + khu * 128 * 16;
    if (v < VD) {
        if (TRANS) {
            const float* wp = W + (size_t)(khu * 128) * VD + v;   // coalesced over v
#pragma unroll 4
            for (int k = 0; k < 128; k++) {
                float w = wp[(size_t)k * VD];
                const float* xr = xp + k * 16;
#pragma unroll
                for (int bb = 0; bb < 16; bb++) acc[bb] = fmaf(w, xr[bb], acc[bb]);
            }
        } else {
            const float4* wp = (const float4*)(W + (size_t)v * HD + khu * 128);
#pragma unroll 2
            for (int k4 = 0; k4 < 32; k4++) {
                float4 w = wp[k4];
                const float* xr = xp + k4 * 64;
#pragma unroll
                for (int bb = 0; bb < 16; bb++) acc[bb] = fmaf(w.x, xr[bb], acc[bb]);
#pragma unroll
                for (int bb = 0; bb < 16; bb++) acc[bb] = fmaf(w.y, xr[16 + bb], acc[bb]);
#pragma unroll
                for (int bb = 0; bb < 16; bb++) acc[bb] = fmaf(w.z, xr[32 + bb], acc[bb]);
#pragma unroll
                for (int bb = 0; bb < 16; bb++) acc[bb] = fmaf(w.w, xr[48 + bb], acc[bb]);
            }
        }
    }
#pragma unroll
    for (int i = 0; i < 16; i++) red[khu][lane][i] = acc[i];
    __syncthreads();

    // reduce 4 K-partials, e = expf(logit), store unnormalized e to d_out
    const int v_l = tid & 63;
    const int vglob = vb0 + v_l;
    const int bq = (tid >> 6) * 4;
    float fb = (vglob < VD) ? fcb[vglob] : 0.f;
#pragma unroll
    for (int q = 0; q < 4; q++) {
        int bb = bq + q;
        float lg = (red[0][v_l][bb] + red[1][v_l][bb]) + (red[2][v_l][bb] + red[3][v_l][bb]);
        float e = 0.f;
        if (vglob < VD) {
            e = expf(lg + fb);
            dout[((size_t)bb * TT + t) * VD + vglob] = e;
        }
        elds[v_l][bb] = e;
    }
    __syncthreads();

    // per-b: block sum of e, top-10 of e*history (ties -> lower index)
    for (int q = 0; q < 4; q++) {
        int bb = wave * 4 + q;
        float e0 = elds[lane][bb];
        float s = e0;
#pragma unroll
        for (int m = 1; m < 64; m <<= 1) s += __shfl_xor(s, m, 64);
        int i0 = vb0 + lane;
        float h0 = (i0 < VD) ? hist[(size_t)bb * VD + i0] : 0.f;
        float k0 = e0 * h0;
        for (int r = 0; r < 10; r++) {
            float cvv = k0; int cii = i0;
#pragma unroll
            for (int m = 1; m < 64; m <<= 1) {
                float ov = __shfl_xor(cvv, m, 64);
                int   oi = __shfl_xor(cii, m, 64);
                if (ov > cvv || (ov == cvv && oi < cii)) { cvv = ov; cii = oi; }
            }
            if (lane == 0) {
                size_t o = ((size_t)blockIdx.x * 16 + bb) * 10 + r;
                tv_ws[o] = cvv; ti_ws[o] = cii;
            }
            if (cii == i0) k0 = -1.f;  // exclude winner
        }
        if (lane == 0) s_ws[blockIdx.x * 16 + bb] = s;
    }
}

// Merge per-block top-10s -> global top-10; hit/selection; state update; value head.
__global__ __launch_bounds__(256) void k5_merge(const float* __restrict__ s_ws,
                                                const float* __restrict__ tv_ws,
                                                const int* __restrict__ ti_ws,
                                                const float* __restrict__ ui,
                                                const float* __restrict__ emb,
                                                const float* __restrict__ x2T,
                                                const float* __restrict__ vw,
                                                const float* __restrict__ vbias,
                                                float* __restrict__ hist,
                                                float* __restrict__ x0,
                                                float* __restrict__ dout,
                                                float* __restrict__ invS,
                                                int t)
{
    const int b = blockIdx.x, tid = threadIdx.x;
    __shared__ float cv[7824];
    __shared__ unsigned short ci16[7824];
    __shared__ float rv[256]; __shared__ int ri[256]; __shared__ int rs[256];
    __shared__ float t10v[10]; __shared__ int t10i[10];
    __shared__ float ifl[10], ev[10];
    __shared__ int s_sel; __shared__ float s_hff;

    for (int c = tid; c < 7820; c += 256) {
        int j = c / 10, r = c % 10;
        cv[c] = tv_ws[((size_t)j * 16 + b) * 10 + r];
        ci16[c] = (unsigned short)ti_ws[((size_t)j * 16 + b) * 10 + r];
    }
    if (tid < 4) { cv[7820 + tid] = -1e30f; ci16[7820 + tid] = 65535; }
    __syncthreads();

    for (int r = 0; r < 10; r++) {
        float bv = -1e30f; int bi = 0x7fffffff, bs = 0;
        for (int c = tid; c < 7820; c += 256) {
            float vv = cv[c]; int ii = (int)ci16[c];
            if (vv > bv || (vv == bv && ii < bi)) { bv = vv; bi = ii; bs = c; }
        }
        rv[tid] = bv; ri[tid] = bi; rs[tid] = bs;
        __syncthreads();
        for (int s = 128; s > 0; s >>= 1) {
            if (tid < s) {
                float ov = rv[tid + s]; int oi = ri[tid + s];
                if (ov > rv[tid] || (ov == rv[tid] && oi < ri[tid])) {
                    rv[tid] = ov; ri[tid] = oi; rs[tid] = rs[tid + s];
                }
            }
            __syncthreads();
        }
        if (tid == 0) { t10v[r] = rv[0]; t10i[r] = ri[0]; cv[rs[0]] = -1e30f; }
        __syncthreads();
    }

    // S = sum of per-block sums (fixed order)
    float sp = 0.f;
    for (int c = tid; c < NB3; c += 256) sp += s_ws[c * 16 + b];
    rv[tid] = sp; __syncthreads();
    for (int s = 128; s > 0; s >>= 1) { if (tid < s) rv[tid] += rv[tid + s]; __syncthreads(); }
    float S = rv[0];
    __syncthreads();

    // value head: dot(x2[b], value_w) + value_b
    float vp = x2T[(size_t)tid * 16 + b] * vw[tid] + x2T[(size_t)(tid + 256) * 16 + b] * vw[tid + 256];
    rv[tid] = vp; __syncthreads();
    for (int s = 128; s > 0; s >>= 1) { if (tid < s) rv[tid] += rv[tid + s]; __syncthreads(); }

    // gather interesting flags + unnormalized policy of the top-10
    if (tid < 10) {
        int ii = t10i[tid];
        ifl[tid] = ui[(size_t)b * VD + ii];
        ev[tid] = dout[((size_t)b * TT + t) * VD + ii];
    }
    __syncthreads();

    if (tid == 0) {
        int hff = 0; float bv = -1e30f; int bsel = -1;
        for (int r = 0; r < 10; r++) {
            if (ifl[r] != 0.f) {
                if (!hff || ev[r] > bv) { bv = ev[r]; bsel = t10i[r]; }
                hff = 1;
            }
        }
        int sel = hff ? bsel : t10i[0];
        s_sel = sel; s_hff = (float)hff;
        dout[O_IDS + b * TT + t] = (float)sel;
        dout[O_HIT + b * TT + t] = (float)hff;
        dout[O_VAL + b * TT + t] = rv[0] + vbias[0];
        invS[b] = 1.f / S;
        if (hff) hist[(size_t)b * VD + sel] -= 1.f;
    }
    __syncthreads();
    float f = 2.f * s_hff - 1.f;
    x0[(size_t)b * HD + tid]       = f * emb[(size_t)s_sel * HD + tid];
    x0[(size_t)b * HD + tid + 256] = f * emb[(size_t)s_sel * HD + tid + 256];
}

__global__ __launch_bounds__(256) void k_final(float* __restrict__ dout,
                                               const float4* __restrict__ hist4,
                                               const float* __restrict__ invS)
{
    for (int idx = blockIdx.x * 256 + threadIdx.x; idx < 400000; idx += 256 * 256) {
        if (idx < 200000) {
            int b = idx / 12500, v4 = idx % 12500;
            float4* row = (float4*)(dout + ((size_t)b * TT + 31) * VD);
            float4 e = row[v4]; float s = invS[b];
            e.x *= s; e.y *= s; e.z *= s; e.w *= s;
            row[v4] = e;
        } else {
            int c = idx - 200000;
            ((float4*)(dout + O_FH))[c] = hist4[c];
        }
    }
}

extern "C" void kernel_launch(void* const* d_in, const int* in_sizes, int n_in,
                              void* d_out, int out_size, void* d_ws, size_t ws_size,
                              hipStream_t stream)
{
    const float* ui   = (const float*)d_in[0];
    const float* mask = (const float*)d_in[1];
    const float* emb  = (const float*)d_in[2];
    const float* wih  = (const float*)d_in[3];
    // d_in[4] = gru_w_hh: unused (hidden state is always zero)
    const float* gbih = (const float*)d_in[5];
    const float* gbhh = (const float*)d_in[6];
    const float* fcw  = (const float*)d_in[7];
    const float* fcb  = (const float*)d_in[8];
    const float* vw   = (const float*)d_in[9];
    const float* vb   = (const float*)d_in[10];
    float* out = (float*)d_out;

    float* wsf  = (float*)d_ws;
    float* hist = wsf + WS_HIST;
    float* x0   = wsf + WS_X0;
    float* x1   = wsf + WS_X1;
    float* x2T  = wsf + WS_X2T;
    float* sws  = wsf + WS_SWS;
    float* tvws = wsf + WS_TV;
    float* invS = wsf + WS_INVS;
    int*   tiws = (int*)(wsf + WS_TI);
    float* fcwT = wsf + WS_FCWT;
    const bool use_t = ws_size >= (size_t)(WS_FCWT + (size_t)HD * VD) * 4;

    k_init<<<256, 256, 0, stream>>>((const float4*)mask, (const float4*)emb,
                                    (float4*)hist, (float4*)x0);
    if (use_t) k_transpose<<<6256, 256, 0, stream>>>(fcw, fcwT);

    for (int t = 0; t < TT; t++) {
        k_gru<<<384, 256, 0, stream>>>(x0, x1, wih, gbih, gbhh, 0, out, invS, t - 1);
        k_gru<<<128, 256, 0, stream>>>(x1, x2T, wih + 786432, gbih + 1536, gbhh + 1536,
                                       1, out, invS, -1);
        if (use_t) k3_fc<1><<<NB3, 256, 0, stream>>>(fcwT, fcb, x2T, hist, out, sws, tvws, tiws, t);
        else       k3_fc<0><<<NB3, 256, 0, stream>>>(fcw,  fcb, x2T, hist, out, sws, tvws, tiws, t);
        k5_merge<<<16, 256, 0, stream>>>(sws, tvws, tiws, ui, emb, x2T, vw, vb,
                                         hist, x0, out, invS, t);
    }
    k_final<<<256, 256, 0, stream>>>(out, (const float4*)hist, invS);
}